// Round 13
// baseline (432.950 us; speedup 1.0000x reference)
//
#include <hip/hip_runtime.h>
#include <hip/hip_bf16.h>
#include <cstdint>
#include <cstddef>

#define TOKENS 4096
#define DM     1024
#define DFF    4096
#define NE     15     // router experts
#define DFR    2048   // router expert hidden (and shared half)
#define NEX    17     // 15 router + 2 shared halves
#define MAXT   176    // 128-row M-tiles: router <=111 + 64 shared

typedef float f32x4 __attribute__((ext_vector_type(4)));
typedef int   i32x4 __attribute__((ext_vector_type(4)));

__device__ __forceinline__ void mfma_16x16x32_bf16(f32x4& d, i32x4 a, i32x4 b){
  asm("v_mfma_f32_16x16x32_bf16 %0, %1, %2, %0" : "+v"(d) : "v"(a), "v"(b));
}

__device__ __forceinline__ void gload16(const void* g, void* l){
  __builtin_amdgcn_global_load_lds(
      (const __attribute__((address_space(1))) uint32_t*)g,
      (__attribute__((address_space(3))) uint32_t*)l, 16, 0, 0);
}

__device__ __forceinline__ unsigned short f2bf(float f){
  unsigned u = __float_as_uint(f);
  u += 0x7FFFu + ((u >> 16) & 1u);      // round-to-nearest-even
  return (unsigned short)(u >> 16);
}

// tanh-form GELU (R10-proven; error <~5e-3/elem, <~1e-3 after W2).
__device__ __forceinline__ float gelu_fast(float v){
  float u = 1.5957691216057308f * (v + 0.044715f * v * v * v);
  float e = __expf(-u);
  return v / (1.0f + e);
}

// ---------------- prep: transpose-cast, 64x64 tiles (R12-proven) ----------------

__global__ void tcast64_kernel(const float* __restrict__ src, ushort* __restrict__ dst,
                               int R, int C){
  __shared__ float tile[64][65];
  const size_t bo = (size_t)blockIdx.z * (size_t)R * C;
  const int c0 = blockIdx.x*64, r0 = blockIdx.y*64;
  const int tid = threadIdx.x;            // 256
  const int lr  = tid >> 4;               // 0..15
  const int lc4 = (tid & 15) * 4;         // 0,4,...,60
  #pragma unroll
  for (int i=0;i<4;i++){
    const int r = lr + i*16;
    float4 v = *reinterpret_cast<const float4*>(src + bo + (size_t)(r0+r)*C + c0 + lc4);
    tile[r][lc4+0]=v.x; tile[r][lc4+1]=v.y; tile[r][lc4+2]=v.z; tile[r][lc4+3]=v.w;
  }
  __syncthreads();
  #pragma unroll
  for (int i=0;i<4;i++){
    const int c = lr + i*16;
    ushort4 o;
    o.x = f2bf(tile[lc4+0][c]);
    o.y = f2bf(tile[lc4+1][c]);
    o.z = f2bf(tile[lc4+2][c]);
    o.w = f2bf(tile[lc4+3][c]);
    *reinterpret_cast<ushort4*>(dst + bo + (size_t)(c0+c)*R + r0 + lc4) = o;
  }
}

// ---------------- gating (fused x->bf16 cast + per-token top-3, NO atomics) ----

__global__ void gate_kernel(const float* __restrict__ x, const float* __restrict__ gW,
                            const float* __restrict__ gb, ushort* __restrict__ xb,
                            int* __restrict__ tokexp, float* __restrict__ tokp){
  const int wave = threadIdx.x >> 6, lane = threadIdx.x & 63;
  const int token = blockIdx.x*4 + wave;
  const float* xr = x + (size_t)token * DM;
  float a[NE];
  #pragma unroll
  for (int e=0;e<NE;e++) a[e] = 0.f;
  const int d0 = lane * 16;
  float xv[16];
  #pragma unroll
  for (int j=0;j<4;j++){
    float4 v = reinterpret_cast<const float4*>(xr + d0)[j];
    xv[j*4+0]=v.x; xv[j*4+1]=v.y; xv[j*4+2]=v.z; xv[j*4+3]=v.w;
  }
  {
    ushort o[16];
    #pragma unroll
    for (int j=0;j<16;j++) o[j] = f2bf(xv[j]);
    ushort* dst = xb + (size_t)token*DM + d0;
    *reinterpret_cast<i32x4*>(dst)     = *reinterpret_cast<const i32x4*>(&o[0]);
    *reinterpret_cast<i32x4*>(dst + 8) = *reinterpret_cast<const i32x4*>(&o[8]);
  }
  for (int j=0;j<16;j++){
    const float* gr = gW + (size_t)(d0 + j) * NE;
    #pragma unroll
    for (int e=0;e<NE;e++) a[e] += xv[j]*gr[e];
  }
  #pragma unroll
  for (int e=0;e<NE;e++){
    for (int off=32; off; off>>=1) a[e] += __shfl_xor(a[e], off, 64);
  }
  if (lane == 0){
    float l[NE], p[NE];
    float m = -1e30f;
    for (int e=0;e<NE;e++){ l[e] = a[e] + gb[e]; m = fmaxf(m, l[e]); }
    float s = 0.f;
    for (int e=0;e<NE;e++){ p[e] = expf(l[e]-m); s += p[e]; }
    float inv = 1.f/s;
    unsigned used = 0;
    for (int k=0;k<3;k++){
      int best = -1; float bv = -1e30f;
      for (int e=0;e<NE;e++) if (!((used>>e)&1u) && l[e] > bv){ bv = l[e]; best = e; }
      used |= 1u<<best;
      tokexp[token*3 + k] = best;
      tokp[token*3 + k]   = p[best]*inv;
    }
  }
}

// ---------------- gating (phase B: deterministic slot assignment, 1 block) ----
// Builds the dense 128-row M-tile table (contiguous active prefix).

__global__ void assign_kernel(const int* __restrict__ tokexp, const float* __restrict__ tokp,
                              int* __restrict__ counts, int* __restrict__ bases,
                              int* __restrict__ tokidx, float* __restrict__ gatev,
                              int* __restrict__ tokslot,
                              int* __restrict__ tile_e, int* __restrict__ tile_by,
                              int* __restrict__ ntiles){
  __shared__ int lh[256][NE];      // per-thread-chunk histogram
  const int tid = threadIdx.x;
  const int t0 = tid * 16;

  int le[48];                      // this chunk's expert picks (16 tokens x 3)
  #pragma unroll
  for (int e=0;e<NE;e++) lh[tid][e] = 0;
  #pragma unroll
  for (int j=0;j<48;j++){
    int e = tokexp[t0*3 + j];
    le[j] = e;
    lh[tid][e]++;
  }
  __syncthreads();
  if (tid < NE){
    int run = 0;
    for (int i=0;i<256;i++){
      int v = lh[i][tid];
      lh[i][tid] = run;
      run += v;
    }
    counts[tid] = run;
  }
  __syncthreads();
  if (tid == 0){
    int b = 0, t = 0;
    for (int e=0;e<NE;e++){
      int c = counts[e];
      int prows = ((c+127)>>7)<<7;        // 128-aligned padded rows
      bases[e] = b; b += prows;
      int nb = prows >> 7;
      for (int j=0;j<nb && t<MAXT;j++){ tile_e[t]=e; tile_by[t]=j; t++; }
    }
    bases[NE] = b; bases[NE+1] = b + TOKENS;
    for (int e=NE;e<NEX;e++){
      for (int j=0;j<32 && t<MAXT;j++){ tile_e[t]=e; tile_by[t]=j; t++; }
    }
    ntiles[0] = t;
  }
  __syncthreads();
  #pragma unroll
  for (int j=0;j<48;j++){
    const int t = t0 + (j/3), k = j - (j/3)*3;
    const int e = le[j];
    const int slot = lh[tid][e]++;
    const int idx = e*TOKENS + slot;
    tokidx[idx] = t;
    gatev[idx]  = tokp[t*3 + k];
    tokslot[t*3 + k] = idx;
  }
}

// ---------------- grouped GEMM 1: h = gelu(x @ W1 + b1) ----------------
// grid (MAXT, 16), block 256. Tile 128x128, BK=64. R10-proven inner loop.
// TILE index is blockIdx.x (fastest): consecutive blocks walk M-tiles within
// one expert at fixed bx -> they share the same 256KB B weight panel in L2
// (R12 had bx fastest: every expert panel re-fetched per M-tile, 2.4x HBM
// over-fetch; per-K-step vmcnt(0) drain then pays HBM-miss latency).

__global__ __launch_bounds__(256,3) void gemm1_kernel(
    const ushort* __restrict__ xb, const ushort* __restrict__ rW1T,
    const ushort* __restrict__ sW1T, const float* __restrict__ rb1,
    const float* __restrict__ sb1, const int* __restrict__ counts,
    const int* __restrict__ bases, const int* __restrict__ tokidx,
    const int* __restrict__ tile_e, const int* __restrict__ tile_by,
    const int* __restrict__ ntiles, ushort* __restrict__ h)
{
  const int ty = blockIdx.x;
  if (ty >= ntiles[0]) return;
  const int e = tile_e[ty], by = tile_by[ty], bx = blockIdx.y;
  const int cnt = (e < NE) ? counts[e] : TOKENS;

  __shared__ __align__(16) ushort lA[128*64];
  __shared__ __align__(16) ushort lB[128*64];

  const int tid = threadIdx.x, wave = tid >> 6, lane = tid & 63;
  const int wr = wave >> 1, wc = wave & 1;

  const ushort* Bp = (e < NE) ? (rW1T + ((size_t)e*DFR + (size_t)bx*128)*DM)
                              : (sW1T + ((size_t)(e-NE)*DFR + (size_t)bx*128)*DM);

  const ushort* srcA[4];
  const ushort* srcB[4];
  unsigned ldso[4];
  #pragma unroll
  for (int i=0;i<4;i++){
    const int rt = i*32 + wave*8 + (lane>>3);
    const int gr = by*128 + rt;
    const int tok = (e < NE) ? tokidx[e*TOKENS + (gr < cnt ? gr : cnt-1)] : gr;
    srcA[i] = xb + (size_t)tok*DM + (lane&7)*8;
    srcB[i] = Bp + (size_t)rt*DM + (lane&7)*8;
    ldso[i] = (unsigned)(i*4096 + wave*1024 + lane*16);
  }

  f32x4 acc[4][4];
  #pragma unroll
  for (int m=0;m<4;m++){
    #pragma unroll
    for (int n=0;n<4;n++){ acc[m][n] = (f32x4){0.f,0.f,0.f,0.f}; }
  }

  for (int k0=0; k0<DM; k0+=64){
    __syncthreads();
    #pragma unroll
    for (int i=0;i<4;i++){ gload16(srcA[i]+k0, (char*)lA + ldso[i]); }
    #pragma unroll
    for (int i=0;i<4;i++){ gload16(srcB[i]+k0, (char*)lB + ldso[i]); }
    __syncthreads();
    #pragma unroll
    for (int kk=0; kk<2; kk++){
      i32x4 af[4], bfr[4];
      #pragma unroll
      for (int m=0;m<4;m++){
        af[m] = *(const i32x4*)((const char*)lA + ((wr*64 + m*16 + (lane&15))*128 + kk*64 + (lane>>4)*16));
      }
      #pragma unroll
      for (int n=0;n<4;n++){
        bfr[n] = *(const i32x4*)((const char*)lB + ((wc*64 + n*16 + (lane&15))*128 + kk*64 + (lane>>4)*16));
      }
      #pragma unroll
      for (int m=0;m<4;m++){
        #pragma unroll
        for (int n=0;n<4;n++){ mfma_16x16x32_bf16(acc[m][n], af[m], bfr[n]); }
      }
    }
  }

  const int hb = bases[e];
  const float* b1p = (e < NE) ? (rb1 + e*DFR + bx*128) : (sb1 + (e-NE)*DFR + bx*128);
  #pragma unroll
  for (int m=0;m<4;m++){
    #pragma unroll
    for (int n=0;n<4;n++){
      const int c = wc*64 + n*16 + (lane & 15);
      const float bias = b1p[c];
      #pragma unroll
      for (int i=0;i<4;i++){
        const int r = wr*64 + m*16 + (lane>>4)*4 + i;
        float v = acc[m][n][i] + bias;
        h[(size_t)(hb + by*128 + r)*DFR + (size_t)bx*128 + c] = f2bf(gelu_fast(v));
      }
    }
  }
}

// ---------------- grouped GEMM 2: rout[row] = h @ W2 + b2 (bf16, no gate) ----
// grid (MAXT, 8), block 256. Tile index fastest (same L2-reuse argument;
// B panel = 512KB per (e,bx), shared by all consecutive tiles of expert e).

__global__ __launch_bounds__(256,3) void gemm2_kernel(
    const ushort* __restrict__ hbuf, const ushort* __restrict__ rW2T,
    const ushort* __restrict__ sW2T, const float* __restrict__ rb2,
    const float* __restrict__ sb2, const int* __restrict__ counts,
    const int* __restrict__ bases,
    const int* __restrict__ tile_e, const int* __restrict__ tile_by,
    const int* __restrict__ ntiles, ushort* __restrict__ rout)
{
  const int ty = blockIdx.x;
  if (ty >= ntiles[0]) return;
  const int e = tile_e[ty], by = tile_by[ty], bx = blockIdx.y;

  __shared__ __align__(16) ushort lA[128*64];
  __shared__ __align__(16) ushort lB[128*64];

  const int tid = threadIdx.x, wave = tid >> 6, lane = tid & 63;
  const int wr = wave >> 1, wc = wave & 1;

  const int hb = bases[e];
  const ushort* Ab = hbuf + (size_t)(hb + by*128)*DFR;
  const ushort* Bp; size_t ldb;
  if (e < NE){ Bp = rW2T + ((size_t)e*DM + (size_t)bx*128)*DFR; ldb = DFR; }
  else       { Bp = sW2T + (size_t)(bx*128)*DFF + (size_t)(e-NE)*DFR; ldb = DFF; }

  const ushort* srcA[4];
  const ushort* srcB[4];
  unsigned ldso[4];
  #pragma unroll
  for (int i=0;i<4;i++){
    const int rt = i*32 + wave*8 + (lane>>3);
    srcA[i] = Ab + (size_t)rt*DFR + (lane&7)*8;
    srcB[i] = Bp + (size_t)rt*ldb + (lane&7)*8;
    ldso[i] = (unsigned)(i*4096 + wave*1024 + lane*16);
  }

  f32x4 acc[4][4];
  #pragma unroll
  for (int m=0;m<4;m++){
    #pragma unroll
    for (int n=0;n<4;n++){ acc[m][n] = (f32x4){0.f,0.f,0.f,0.f}; }
  }

  for (int k0=0; k0<DFR; k0+=64){
    __syncthreads();
    #pragma unroll
    for (int i=0;i<4;i++){ gload16(srcA[i]+k0, (char*)lA + ldso[i]); }
    #pragma unroll
    for (int i=0;i<4;i++){ gload16(srcB[i]+k0, (char*)lB + ldso[i]); }
    __syncthreads();
    #pragma unroll
    for (int kk=0; kk<2; kk++){
      i32x4 af[4], bfr[4];
      #pragma unroll
      for (int m=0;m<4;m++){
        af[m] = *(const i32x4*)((const char*)lA + ((wr*64 + m*16 + (lane&15))*128 + kk*64 + (lane>>4)*16));
      }
      #pragma unroll
      for (int n=0;n<4;n++){
        bfr[n] = *(const i32x4*)((const char*)lB + ((wc*64 + n*16 + (lane&15))*128 + kk*64 + (lane>>4)*16));
      }
      #pragma unroll
      for (int m=0;m<4;m++){
        #pragma unroll
        for (int n=0;n<4;n++){ mfma_16x16x32_bf16(acc[m][n], af[m], bfr[n]); }
      }
    }
  }

  #pragma unroll
  for (int m=0;m<4;m++){
    #pragma unroll
    for (int n=0;n<4;n++){
      const int c  = wc*64 + n*16 + (lane & 15);
      const int cg = bx*128 + c;
      const float bias = (e < NE) ? rb2[e*DM + cg] : ((e == NE) ? sb2[cg] : 0.f);
      #pragma unroll
      for (int i=0;i<4;i++){
        const int r = wr*64 + m*16 + (lane>>4)*4 + i;
        rout[(size_t)(hb + by*128 + r)*DM + cg] = f2bf(acc[m][n][i] + bias);
      }
    }
  }
}

// ---------------- combine: out = x + sh0 + sh1 + sum_k gate_k * rout ----------

__global__ void combine_kernel(const float* __restrict__ x, const ushort* __restrict__ rout,
                               const int* __restrict__ bases, const int* __restrict__ tokslot,
                               const float* __restrict__ gatev, float* __restrict__ out)
{
  const int wave = threadIdx.x >> 6, lane = threadIdx.x & 63;
  const int token = blockIdx.x*4 + wave;
  const int d0 = lane*16;

  float acc[16];
  #pragma unroll
  for (int j=0;j<4;j++){
    float4 v = reinterpret_cast<const float4*>(x + (size_t)token*DM + d0)[j];
    acc[j*4+0]=v.x; acc[j*4+1]=v.y; acc[j*4+2]=v.z; acc[j*4+3]=v.w;
  }

  int   rows[5];
  float gs[5];
  rows[0] = bases[NE]   + token; gs[0] = 1.f;
  rows[1] = bases[NE+1] + token; gs[1] = 1.f;
  #pragma unroll
  for (int k=0;k<3;k++){
    const int idx = tokslot[token*3 + k];
    const int e = idx >> 12, s = idx & (TOKENS-1);
    rows[2+k] = bases[e] + s;
    gs[2+k] = gatev[idx];
  }

  #pragma unroll
  for (int q=0;q<5;q++){
    const float g = gs[q];
    const ushort* rp = rout + (size_t)rows[q]*DM + d0;
    #pragma unroll
    for (int hh=0;hh<2;hh++){
      i32x4 v = *reinterpret_cast<const i32x4*>(rp + hh*8);
      #pragma unroll
      for (int j=0;j<4;j++){
        const unsigned u = (unsigned)v[j];
        acc[hh*8 + j*2 + 0] += g * __uint_as_float(u << 16);
        acc[hh*8 + j*2 + 1] += g * __uint_as_float(u & 0xFFFF0000u);
      }
    }
  }

  #pragma unroll
  for (int j=0;j<4;j++){
    float4 v; v.x=acc[j*4+0]; v.y=acc[j*4+1]; v.z=acc[j*4+2]; v.w=acc[j*4+3];
    reinterpret_cast<float4*>(out + (size_t)token*DM + d0)[j] = v;
  }
}

// ---------------- launcher ----------------

extern "C" void kernel_launch(void* const* d_in, const int* in_sizes, int n_in,
                              void* d_out, int out_size, void* d_ws, size_t ws_size,
                              hipStream_t stream)
{
  (void)in_sizes; (void)n_in; (void)out_size; (void)ws_size;
  const float* x   = (const float*)d_in[0];
  const float* sW1 = (const float*)d_in[1];
  const float* sb1 = (const float*)d_in[2];
  const float* sW2 = (const float*)d_in[3];
  const float* sb2 = (const float*)d_in[4];
  const float* rW1 = (const float*)d_in[5];
  const float* rb1 = (const float*)d_in[6];
  const float* rW2 = (const float*)d_in[7];
  const float* rb2 = (const float*)d_in[8];
  const float* gW  = (const float*)d_in[9];
  const float* gb  = (const float*)d_in[10];
  float* out = (float*)d_out;

  char* ws = (char*)d_ws;
  ushort* xb   = (ushort*)(ws + 0);          //  8,388,608  x bf16 [4096][1024]
  ushort* sW1T = (ushort*)(ws + 8388608);    //  8,388,608  [4096][1024]
  ushort* sW2T = (ushort*)(ws + 16777216);   //  8,388,608  [1024][4096]
  ushort* rW1T = (ushort*)(ws + 25165824);   // 62,914,560  [15][2048][1024]
  ushort* rW2T = (ushort*)(ws + 88080384);   // 62,914,560  [15][1024][2048]
  ushort* hbuf = (ushort*)(ws + 150994944);  // 92,274,688  [22528][2048]
  // rout ALIASES rW1T's region: rW1T is dead after gemm1, rout written by gemm2.
  ushort* rout = (ushort*)(ws + 25165824);   // 46,137,344  [22528][1024]
  int*   counts  = (int*)(ws + 243269632);
  int*   bases   = (int*)(ws + 243269760);
  int*   tokidx  = (int*)(ws + 243270144);   // 15*4096 ints
  float* gatev   = (float*)(ws + 243515904); // 15*4096 floats
  int*   tokslot = (int*)(ws + 243761664);   // 4096*3 ints
  int*   tokexp  = (int*)(ws + 243810816);   // 4096*3 ints
  float* tokp    = (float*)(ws + 243859968); // 4096*3 floats
  int*   tile_e  = (int*)(ws + 243909120);   // MAXT ints
  int*   tile_by = (int*)(ws + 243910144);
  int*   ntiles  = (int*)(ws + 243911168);
  // total ~244 MB of workspace

  tcast64_kernel<<<dim3(DFF/64, DM/64, 1),  dim3(256), 0, stream>>>(sW1, sW1T, DM, DFF);
  tcast64_kernel<<<dim3(DM/64, DFF/64, 1),  dim3(256), 0, stream>>>(sW2, sW2T, DFF, DM);
  tcast64_kernel<<<dim3(DFR/64, DM/64, NE), dim3(256), 0, stream>>>(rW1, rW1T, DM, DFR);
  tcast64_kernel<<<dim3(DM/64, DFR/64, NE), dim3(256), 0, stream>>>(rW2, rW2T, DFR, DM);

  gate_kernel<<<dim3(TOKENS/4), dim3(256), 0, stream>>>(x, gW, gb, xb, tokexp, tokp);
  assign_kernel<<<dim3(1), dim3(256), 0, stream>>>(tokexp, tokp, counts, bases,
                                                   tokidx, gatev, tokslot,
                                                   tile_e, tile_by, ntiles);

  gemm1_kernel<<<dim3(MAXT,16), dim3(256), 0, stream>>>(
      xb, rW1T, sW1T, rb1, sb1, counts, bases, tokidx, tile_e, tile_by, ntiles, hbuf);
  gemm2_kernel<<<dim3(MAXT,8), dim3(256), 0, stream>>>(
      hbuf, rW2T, sW2T, rb2, sb2, counts, bases, tile_e, tile_by, ntiles, rout);
  combine_kernel<<<dim3(TOKENS/4), dim3(256), 0, stream>>>(
      x, rout, bases, tokslot, gatev, out);
}

// Round 14
// 397.019 us; speedup vs baseline: 1.0905x; 1.0905x over previous
//
#include <hip/hip_runtime.h>
#include <hip/hip_bf16.h>
#include <cstdint>
#include <cstddef>

#define TOKENS 4096
#define DM     1024
#define DFF    4096
#define NE     15     // router experts
#define DFR    2048   // router expert hidden (and shared half)
#define NEX    17     // 15 router + 2 shared halves
#define MAXT   176    // 128-row M-tiles: router <=111 + 64 shared

typedef float f32x4 __attribute__((ext_vector_type(4)));
typedef int   i32x4 __attribute__((ext_vector_type(4)));

__device__ __forceinline__ void mfma_16x16x32_bf16(f32x4& d, i32x4 a, i32x4 b){
  asm("v_mfma_f32_16x16x32_bf16 %0, %1, %2, %0" : "+v"(d) : "v"(a), "v"(b));
}

__device__ __forceinline__ void gload16(const void* g, void* l){
  __builtin_amdgcn_global_load_lds(
      (const __attribute__((address_space(1))) uint32_t*)g,
      (__attribute__((address_space(3))) uint32_t*)l, 16, 0, 0);
}

__device__ __forceinline__ unsigned short f2bf(float f){
  unsigned u = __float_as_uint(f);
  u += 0x7FFFu + ((u >> 16) & 1u);      // round-to-nearest-even
  return (unsigned short)(u >> 16);
}

// tanh-form GELU (R10-proven; error <~5e-3/elem, <~1e-3 after W2).
__device__ __forceinline__ float gelu_fast(float v){
  float u = 1.5957691216057308f * (v + 0.044715f * v * v * v);
  float e = __expf(-u);
  return v / (1.0f + e);
}

// ---------------- prep: ALL weight transpose-casts in ONE launch ----------------
// 64x64 tiles (R12-proven body). Flat block id decodes {tensor, expert, tile}:
//   [0,1024)      sW1  [1024][4096] -> sW1T [4096][1024]   (nx=64)
//   [1024,2048)   sW2  [4096][1024] -> sW2T [1024][4096]   (nx=16)
//   [2048,9728)   rW1  e=(b-2048)/512, [1024][2048]->[2048][1024] (nx=32)
//   [9728,17408)  rW2  e=(b-9728)/512, [2048][1024]->[1024][2048] (nx=16)
// Merging removes 3 launch gaps + 3 dispatch-tail drains (~10-15us).

__global__ void tcast_all_kernel(const float* __restrict__ sW1, const float* __restrict__ sW2,
                                 const float* __restrict__ rW1, const float* __restrict__ rW2,
                                 ushort* __restrict__ sW1T, ushort* __restrict__ sW2T,
                                 ushort* __restrict__ rW1T, ushort* __restrict__ rW2T){
  int b = blockIdx.x;
  const float* src; ushort* dst; int R, C;
  if (b < 1024){
    src = sW1; dst = sW1T; R = DM; C = DFF;
  } else if (b < 2048){
    b -= 1024; src = sW2; dst = sW2T; R = DFF; C = DM;
  } else if (b < 9728){
    b -= 2048; const int e = b >> 9; b &= 511;
    src = rW1 + (size_t)e*DM*DFR; dst = rW1T + (size_t)e*DM*DFR; R = DM; C = DFR;
  } else {
    b -= 9728; const int e = b >> 9; b &= 511;
    src = rW2 + (size_t)e*DFR*DM; dst = rW2T + (size_t)e*DFR*DM; R = DFR; C = DM;
  }
  const int nx = C >> 6;
  const int c0 = (b % nx) * 64, r0 = (b / nx) * 64;

  __shared__ float tile[64][65];
  const int tid = threadIdx.x;            // 256
  const int lr  = tid >> 4;               // 0..15
  const int lc4 = (tid & 15) * 4;         // 0,4,...,60
  #pragma unroll
  for (int i=0;i<4;i++){
    const int r = lr + i*16;
    float4 v = *reinterpret_cast<const float4*>(src + (size_t)(r0+r)*C + c0 + lc4);
    tile[r][lc4+0]=v.x; tile[r][lc4+1]=v.y; tile[r][lc4+2]=v.z; tile[r][lc4+3]=v.w;
  }
  __syncthreads();
  #pragma unroll
  for (int i=0;i<4;i++){
    const int c = lr + i*16;
    ushort4 o;
    o.x = f2bf(tile[lc4+0][c]);
    o.y = f2bf(tile[lc4+1][c]);
    o.z = f2bf(tile[lc4+2][c]);
    o.w = f2bf(tile[lc4+3][c]);
    *reinterpret_cast<ushort4*>(dst + (size_t)(c0+c)*R + r0 + lc4) = o;
  }
}

// ---------------- gating (fused x->bf16 cast + per-token top-3, NO atomics) ----

__global__ void gate_kernel(const float* __restrict__ x, const float* __restrict__ gW,
                            const float* __restrict__ gb, ushort* __restrict__ xb,
                            int* __restrict__ tokexp, float* __restrict__ tokp){
  const int wave = threadIdx.x >> 6, lane = threadIdx.x & 63;
  const int token = blockIdx.x*4 + wave;
  const float* xr = x + (size_t)token * DM;
  float a[NE];
  #pragma unroll
  for (int e=0;e<NE;e++) a[e] = 0.f;
  const int d0 = lane * 16;
  float xv[16];
  #pragma unroll
  for (int j=0;j<4;j++){
    float4 v = reinterpret_cast<const float4*>(xr + d0)[j];
    xv[j*4+0]=v.x; xv[j*4+1]=v.y; xv[j*4+2]=v.z; xv[j*4+3]=v.w;
  }
  {
    ushort o[16];
    #pragma unroll
    for (int j=0;j<16;j++) o[j] = f2bf(xv[j]);
    ushort* dst = xb + (size_t)token*DM + d0;
    *reinterpret_cast<i32x4*>(dst)     = *reinterpret_cast<const i32x4*>(&o[0]);
    *reinterpret_cast<i32x4*>(dst + 8) = *reinterpret_cast<const i32x4*>(&o[8]);
  }
  for (int j=0;j<16;j++){
    const float* gr = gW + (size_t)(d0 + j) * NE;
    #pragma unroll
    for (int e=0;e<NE;e++) a[e] += xv[j]*gr[e];
  }
  #pragma unroll
  for (int e=0;e<NE;e++){
    for (int off=32; off; off>>=1) a[e] += __shfl_xor(a[e], off, 64);
  }
  if (lane == 0){
    float l[NE], p[NE];
    float m = -1e30f;
    for (int e=0;e<NE;e++){ l[e] = a[e] + gb[e]; m = fmaxf(m, l[e]); }
    float s = 0.f;
    for (int e=0;e<NE;e++){ p[e] = expf(l[e]-m); s += p[e]; }
    float inv = 1.f/s;
    unsigned used = 0;
    for (int k=0;k<3;k++){
      int best = -1; float bv = -1e30f;
      for (int e=0;e<NE;e++) if (!((used>>e)&1u) && l[e] > bv){ bv = l[e]; best = e; }
      used |= 1u<<best;
      tokexp[token*3 + k] = best;
      tokp[token*3 + k]   = p[best]*inv;
    }
  }
}

// ---------------- gating (phase B: deterministic slot assignment, 1 block) ----
// Builds the dense 128-row M-tile table (contiguous active prefix).

__global__ void assign_kernel(const int* __restrict__ tokexp, const float* __restrict__ tokp,
                              int* __restrict__ counts, int* __restrict__ bases,
                              int* __restrict__ tokidx, float* __restrict__ gatev,
                              int* __restrict__ tokslot,
                              int* __restrict__ tile_e, int* __restrict__ tile_by,
                              int* __restrict__ ntiles){
  __shared__ int lh[256][NE];      // per-thread-chunk histogram
  const int tid = threadIdx.x;
  const int t0 = tid * 16;

  int le[48];                      // this chunk's expert picks (16 tokens x 3)
  #pragma unroll
  for (int e=0;e<NE;e++) lh[tid][e] = 0;
  #pragma unroll
  for (int j=0;j<48;j++){
    int e = tokexp[t0*3 + j];
    le[j] = e;
    lh[tid][e]++;
  }
  __syncthreads();
  if (tid < NE){
    int run = 0;
    for (int i=0;i<256;i++){
      int v = lh[i][tid];
      lh[i][tid] = run;
      run += v;
    }
    counts[tid] = run;
  }
  __syncthreads();
  if (tid == 0){
    int b = 0, t = 0;
    for (int e=0;e<NE;e++){
      int c = counts[e];
      int prows = ((c+127)>>7)<<7;        // 128-aligned padded rows
      bases[e] = b; b += prows;
      int nb = prows >> 7;
      for (int j=0;j<nb && t<MAXT;j++){ tile_e[t]=e; tile_by[t]=j; t++; }
    }
    bases[NE] = b; bases[NE+1] = b + TOKENS;
    for (int e=NE;e<NEX;e++){
      for (int j=0;j<32 && t<MAXT;j++){ tile_e[t]=e; tile_by[t]=j; t++; }
    }
    ntiles[0] = t;
  }
  __syncthreads();
  #pragma unroll
  for (int j=0;j<48;j++){
    const int t = t0 + (j/3), k = j - (j/3)*3;
    const int e = le[j];
    const int slot = lh[tid][e]++;
    const int idx = e*TOKENS + slot;
    tokidx[idx] = t;
    gatev[idx]  = tokp[t*3 + k];
    tokslot[t*3 + k] = idx;
  }
}

// ---------------- grouped GEMM 1: h = gelu(x @ W1 + b1) ----------------
// grid (16, MAXT), block 256. Tile 128x128, BK=64. R10/R12-proven structure
// (asm MFMA, VGPR 64, 3 blocks/CU, bx fastest - measured best of both
// grid orderings: R12=403us vs R13 tile-fastest=433us).

__global__ __launch_bounds__(256,3) void gemm1_kernel(
    const ushort* __restrict__ xb, const ushort* __restrict__ rW1T,
    const ushort* __restrict__ sW1T, const float* __restrict__ rb1,
    const float* __restrict__ sb1, const int* __restrict__ counts,
    const int* __restrict__ bases, const int* __restrict__ tokidx,
    const int* __restrict__ tile_e, const int* __restrict__ tile_by,
    const int* __restrict__ ntiles, ushort* __restrict__ h)
{
  const int ty = blockIdx.y;
  if (ty >= ntiles[0]) return;
  const int e = tile_e[ty], by = tile_by[ty], bx = blockIdx.x;
  const int cnt = (e < NE) ? counts[e] : TOKENS;

  __shared__ __align__(16) ushort lA[128*64];
  __shared__ __align__(16) ushort lB[128*64];

  const int tid = threadIdx.x, wave = tid >> 6, lane = tid & 63;
  const int wr = wave >> 1, wc = wave & 1;

  const ushort* Bp = (e < NE) ? (rW1T + ((size_t)e*DFR + (size_t)bx*128)*DM)
                              : (sW1T + ((size_t)(e-NE)*DFR + (size_t)bx*128)*DM);

  const ushort* srcA[4];
  const ushort* srcB[4];
  unsigned ldso[4];
  #pragma unroll
  for (int i=0;i<4;i++){
    const int rt = i*32 + wave*8 + (lane>>3);
    const int gr = by*128 + rt;
    const int tok = (e < NE) ? tokidx[e*TOKENS + (gr < cnt ? gr : cnt-1)] : gr;
    srcA[i] = xb + (size_t)tok*DM + (lane&7)*8;
    srcB[i] = Bp + (size_t)rt*DM + (lane&7)*8;
    ldso[i] = (unsigned)(i*4096 + wave*1024 + lane*16);
  }

  f32x4 acc[4][4];
  #pragma unroll
  for (int m=0;m<4;m++){
    #pragma unroll
    for (int n=0;n<4;n++){ acc[m][n] = (f32x4){0.f,0.f,0.f,0.f}; }
  }

  for (int k0=0; k0<DM; k0+=64){
    __syncthreads();
    #pragma unroll
    for (int i=0;i<4;i++){ gload16(srcA[i]+k0, (char*)lA + ldso[i]); }
    #pragma unroll
    for (int i=0;i<4;i++){ gload16(srcB[i]+k0, (char*)lB + ldso[i]); }
    __syncthreads();
    #pragma unroll
    for (int kk=0; kk<2; kk++){
      i32x4 af[4], bfr[4];
      #pragma unroll
      for (int m=0;m<4;m++){
        af[m] = *(const i32x4*)((const char*)lA + ((wr*64 + m*16 + (lane&15))*128 + kk*64 + (lane>>4)*16));
      }
      #pragma unroll
      for (int n=0;n<4;n++){
        bfr[n] = *(const i32x4*)((const char*)lB + ((wc*64 + n*16 + (lane&15))*128 + kk*64 + (lane>>4)*16));
      }
      #pragma unroll
      for (int m=0;m<4;m++){
        #pragma unroll
        for (int n=0;n<4;n++){ mfma_16x16x32_bf16(acc[m][n], af[m], bfr[n]); }
      }
    }
  }

  const int hb = bases[e];
  const float* b1p = (e < NE) ? (rb1 + e*DFR + bx*128) : (sb1 + (e-NE)*DFR + bx*128);
  #pragma unroll
  for (int m=0;m<4;m++){
    #pragma unroll
    for (int n=0;n<4;n++){
      const int c = wc*64 + n*16 + (lane & 15);
      const float bias = b1p[c];
      #pragma unroll
      for (int i=0;i<4;i++){
        const int r = wr*64 + m*16 + (lane>>4)*4 + i;
        float v = acc[m][n][i] + bias;
        h[(size_t)(hb + by*128 + r)*DFR + (size_t)bx*128 + c] = f2bf(gelu_fast(v));
      }
    }
  }
}

// ---------------- grouped GEMM 2: rout[row] = h @ W2 + b2 (bf16, no gate) ----
// grid (8, MAXT), block 256.

__global__ __launch_bounds__(256,3) void gemm2_kernel(
    const ushort* __restrict__ hbuf, const ushort* __restrict__ rW2T,
    const ushort* __restrict__ sW2T, const float* __restrict__ rb2,
    const float* __restrict__ sb2, const int* __restrict__ counts,
    const int* __restrict__ bases,
    const int* __restrict__ tile_e, const int* __restrict__ tile_by,
    const int* __restrict__ ntiles, ushort* __restrict__ rout)
{
  const int ty = blockIdx.y;
  if (ty >= ntiles[0]) return;
  const int e = tile_e[ty], by = tile_by[ty], bx = blockIdx.x;

  __shared__ __align__(16) ushort lA[128*64];
  __shared__ __align__(16) ushort lB[128*64];

  const int tid = threadIdx.x, wave = tid >> 6, lane = tid & 63;
  const int wr = wave >> 1, wc = wave & 1;

  const int hb = bases[e];
  const ushort* Ab = hbuf + (size_t)(hb + by*128)*DFR;
  const ushort* Bp; size_t ldb;
  if (e < NE){ Bp = rW2T + ((size_t)e*DM + (size_t)bx*128)*DFR; ldb = DFR; }
  else       { Bp = sW2T + (size_t)(bx*128)*DFF + (size_t)(e-NE)*DFR; ldb = DFF; }

  const ushort* srcA[4];
  const ushort* srcB[4];
  unsigned ldso[4];
  #pragma unroll
  for (int i=0;i<4;i++){
    const int rt = i*32 + wave*8 + (lane>>3);
    srcA[i] = Ab + (size_t)rt*DFR + (lane&7)*8;
    srcB[i] = Bp + (size_t)rt*ldb + (lane&7)*8;
    ldso[i] = (unsigned)(i*4096 + wave*1024 + lane*16);
  }

  f32x4 acc[4][4];
  #pragma unroll
  for (int m=0;m<4;m++){
    #pragma unroll
    for (int n=0;n<4;n++){ acc[m][n] = (f32x4){0.f,0.f,0.f,0.f}; }
  }

  for (int k0=0; k0<DFR; k0+=64){
    __syncthreads();
    #pragma unroll
    for (int i=0;i<4;i++){ gload16(srcA[i]+k0, (char*)lA + ldso[i]); }
    #pragma unroll
    for (int i=0;i<4;i++){ gload16(srcB[i]+k0, (char*)lB + ldso[i]); }
    __syncthreads();
    #pragma unroll
    for (int kk=0; kk<2; kk++){
      i32x4 af[4], bfr[4];
      #pragma unroll
      for (int m=0;m<4;m++){
        af[m] = *(const i32x4*)((const char*)lA + ((wr*64 + m*16 + (lane&15))*128 + kk*64 + (lane>>4)*16));
      }
      #pragma unroll
      for (int n=0;n<4;n++){
        bfr[n] = *(const i32x4*)((const char*)lB + ((wc*64 + n*16 + (lane&15))*128 + kk*64 + (lane>>4)*16));
      }
      #pragma unroll
      for (int m=0;m<4;m++){
        #pragma unroll
        for (int n=0;n<4;n++){ mfma_16x16x32_bf16(acc[m][n], af[m], bfr[n]); }
      }
    }
  }

  #pragma unroll
  for (int m=0;m<4;m++){
    #pragma unroll
    for (int n=0;n<4;n++){
      const int c  = wc*64 + n*16 + (lane & 15);
      const int cg = bx*128 + c;
      const float bias = (e < NE) ? rb2[e*DM + cg] : ((e == NE) ? sb2[cg] : 0.f);
      #pragma unroll
      for (int i=0;i<4;i++){
        const int r = wr*64 + m*16 + (lane>>4)*4 + i;
        rout[(size_t)(hb + by*128 + r)*DM + cg] = f2bf(acc[m][n][i] + bias);
      }
    }
  }
}

// ---------------- combine: out = x + sh0 + sh1 + sum_k gate_k * rout ----------

__global__ void combine_kernel(const float* __restrict__ x, const ushort* __restrict__ rout,
                               const int* __restrict__ bases, const int* __restrict__ tokslot,
                               const float* __restrict__ gatev, float* __restrict__ out)
{
  const int wave = threadIdx.x >> 6, lane = threadIdx.x & 63;
  const int token = blockIdx.x*4 + wave;
  const int d0 = lane*16;

  float acc[16];
  #pragma unroll
  for (int j=0;j<4;j++){
    float4 v = reinterpret_cast<const float4*>(x + (size_t)token*DM + d0)[j];
    acc[j*4+0]=v.x; acc[j*4+1]=v.y; acc[j*4+2]=v.z; acc[j*4+3]=v.w;
  }

  int   rows[5];
  float gs[5];
  rows[0] = bases[NE]   + token; gs[0] = 1.f;
  rows[1] = bases[NE+1] + token; gs[1] = 1.f;
  #pragma unroll
  for (int k=0;k<3;k++){
    const int idx = tokslot[token*3 + k];
    const int e = idx >> 12, s = idx & (TOKENS-1);
    rows[2+k] = bases[e] + s;
    gs[2+k] = gatev[idx];
  }

  #pragma unroll
  for (int q=0;q<5;q++){
    const float g = gs[q];
    const ushort* rp = rout + (size_t)rows[q]*DM + d0;
    #pragma unroll
    for (int hh=0;hh<2;hh++){
      i32x4 v = *reinterpret_cast<const i32x4*>(rp + hh*8);
      #pragma unroll
      for (int j=0;j<4;j++){
        const unsigned u = (unsigned)v[j];
        acc[hh*8 + j*2 + 0] += g * __uint_as_float(u << 16);
        acc[hh*8 + j*2 + 1] += g * __uint_as_float(u & 0xFFFF0000u);
      }
    }
  }

  #pragma unroll
  for (int j=0;j<4;j++){
    float4 v; v.x=acc[j*4+0]; v.y=acc[j*4+1]; v.z=acc[j*4+2]; v.w=acc[j*4+3];
    reinterpret_cast<float4*>(out + (size_t)token*DM + d0)[j] = v;
  }
}

// ---------------- launcher ----------------

extern "C" void kernel_launch(void* const* d_in, const int* in_sizes, int n_in,
                              void* d_out, int out_size, void* d_ws, size_t ws_size,
                              hipStream_t stream)
{
  (void)in_sizes; (void)n_in; (void)out_size; (void)ws_size;
  const float* x   = (const float*)d_in[0];
  const float* sW1 = (const float*)d_in[1];
  const float* sb1 = (const float*)d_in[2];
  const float* sW2 = (const float*)d_in[3];
  const float* sb2 = (const float*)d_in[4];
  const float* rW1 = (const float*)d_in[5];
  const float* rb1 = (const float*)d_in[6];
  const float* rW2 = (const float*)d_in[7];
  const float* rb2 = (const float*)d_in[8];
  const float* gW  = (const float*)d_in[9];
  const float* gb  = (const float*)d_in[10];
  float* out = (float*)d_out;

  char* ws = (char*)d_ws;
  ushort* xb   = (ushort*)(ws + 0);          //  8,388,608  x bf16 [4096][1024]
  ushort* sW1T = (ushort*)(ws + 8388608);    //  8,388,608  [4096][1024]
  ushort* sW2T = (ushort*)(ws + 16777216);   //  8,388,608  [1024][4096]
  ushort* rW1T = (ushort*)(ws + 25165824);   // 62,914,560  [15][2048][1024]
  ushort* rW2T = (ushort*)(ws + 88080384);   // 62,914,560  [15][1024][2048]
  ushort* hbuf = (ushort*)(ws + 150994944);  // 92,274,688  [22528][2048]
  // rout ALIASES rW1T's region: rW1T is dead after gemm1, rout written by gemm2.
  ushort* rout = (ushort*)(ws + 25165824);   // 46,137,344  [22528][1024]
  int*   counts  = (int*)(ws + 243269632);
  int*   bases   = (int*)(ws + 243269760);
  int*   tokidx  = (int*)(ws + 243270144);   // 15*4096 ints
  float* gatev   = (float*)(ws + 243515904); // 15*4096 floats
  int*   tokslot = (int*)(ws + 243761664);   // 4096*3 ints
  int*   tokexp  = (int*)(ws + 243810816);   // 4096*3 ints
  float* tokp    = (float*)(ws + 243859968); // 4096*3 floats
  int*   tile_e  = (int*)(ws + 243909120);   // MAXT ints
  int*   tile_by = (int*)(ws + 243910144);
  int*   ntiles  = (int*)(ws + 243911168);
  // total ~244 MB of workspace

  tcast_all_kernel<<<dim3(17408), dim3(256), 0, stream>>>(
      sW1, sW2, rW1, rW2, sW1T, sW2T, rW1T, rW2T);

  gate_kernel<<<dim3(TOKENS/4), dim3(256), 0, stream>>>(x, gW, gb, xb, tokexp, tokp);
  assign_kernel<<<dim3(1), dim3(256), 0, stream>>>(tokexp, tokp, counts, bases,
                                                   tokidx, gatev, tokslot,
                                                   tile_e, tile_by, ntiles);

  gemm1_kernel<<<dim3(16,MAXT), dim3(256), 0, stream>>>(
      xb, rW1T, sW1T, rb1, sb1, counts, bases, tokidx, tile_e, tile_by, ntiles, hbuf);
  gemm2_kernel<<<dim3(8,MAXT), dim3(256), 0, stream>>>(
      hbuf, rW2T, sW2T, rb2, sb2, counts, bases, tile_e, tile_by, ntiles, rout);
  combine_kernel<<<dim3(TOKENS/4), dim3(256), 0, stream>>>(
      x, rout, bases, tokslot, gatev, out);
}